// Round 7
// baseline (129.623 us; speedup 1.0000x reference)
//
#include <hip/hip_runtime.h>

// NCC forward: X,Y (16,32,64,24) fp32, PS=5, D=2, EPS=0.01
// out[blk*184320 + (yo*24+i)*1536 + h*24 + x] =
//   (cross - Em(h,x)*SF(h+yo,i)) * IE(h,x) * IF(h+yo,i)
// cross = sum_{dy,dx} Xp[h+dy][x+dx] * Yp[h+yo+dy][i+dx]
//
// Mapping: thread t = (x4 = t%6, h = t/6); 384 threads = 6 waves; sweep i.
// Each thread owns 4 consecutive x -> float4 stores; wave w writes bytes
// [w*1024,(w+1)*1024) of each 6144B (yo,i)-plane: 1KB contiguous aligned per
// store instruction, block covers whole plane (fill-kernel write pattern).
// X window Xw[5][8] loaded once (covers 4 overlapping 5x5 patches); X stats
// computed in-register. Y window yw[9][5] rolls along i with mod-5
// compile-time slots (step_i<K>). Y staged transposed [col][row] stride 73.

#define NT 384

template<int K>
__device__ __forceinline__ void step_i(
    int i, int h, int t,
    const float* __restrict__ sYT, const float* __restrict__ sFI,
    const float (&Xw)[5][8], float (&yw)[9][5],
    const float (&Em)[4], const float (&IE)[4],
    float* __restrict__ outC)
{
    // roll in Y column i+4 (rows h..h+8) -> slot (K+4)%5
    const float* yc = &sYT[(i + 4) * 73 + h];
    #pragma unroll
    for (int dr = 0; dr < 9; ++dr) yw[dr][(K + 4) % 5] = yc[dr];

    // cross for 4 x-positions x 5 yo: 500 FMA, all register operands
    float cr[4][5];
    #pragma unroll
    for (int q = 0; q < 4; ++q)
        #pragma unroll
        for (int yo = 0; yo < 5; ++yo) cr[q][yo] = 0.f;

    #pragma unroll
    for (int dy = 0; dy < 5; ++dy) {
        #pragma unroll
        for (int dx = 0; dx < 5; ++dx) {
            #pragma unroll
            for (int yo = 0; yo < 5; ++yo) {
                const float yv = yw[dy + yo][(K + dx) % 5];
                #pragma unroll
                for (int q = 0; q < 4; ++q)
                    cr[q][yo] = fmaf(Xw[dy][q + dx], yv, cr[q][yo]);
            }
        }
    }

    // (SF, IF) rows h..h+4 at col i; emit 5 x float4 (1KB/wave contiguous)
    const float2* fi = (const float2*)&sFI[(i * 68 + h) * 2];
    #pragma unroll
    for (int yo = 0; yo < 5; ++yo) {
        float2 f = fi[yo];
        float4 v;
        v.x = fmaf(-Em[0], f.x, cr[0][yo]) * (IE[0] * f.y);
        v.y = fmaf(-Em[1], f.x, cr[1][yo]) * (IE[1] * f.y);
        v.z = fmaf(-Em[2], f.x, cr[2][yo]) * (IE[2] * f.y);
        v.w = fmaf(-Em[3], f.x, cr[3][yo]) * (IE[3] * f.y);
        *(float4*)(outC + (size_t)(yo * 24 + i) * 1536 + 4 * t) = v;
    }
}

__global__ __launch_bounds__(NT, 3)
void ncc_kernel(const float* __restrict__ X, const float* __restrict__ Y,
                float* __restrict__ out)
{
    __shared__ float sXp[68 * 28];        // Xp row-major: row r = X[r-2], col c = X[c-2]
    __shared__ float sYT[28 * 73];        // Yp transposed [col 0..27][row 0..71]
    __shared__ float sFI[24 * 68 * 2];    // (SF, 1/Fs) interleaved per (i, r)

    const int tid = threadIdx.x;
    const int blk = blockIdx.x;           // = b*32 + c
    const float* Xc = X + (size_t)blk * 1536;
    const float* Yc = Y + (size_t)blk * 1536;
    float* outC = out + (size_t)blk * 184320;

    // ---- Phase A: stage padded inputs ----
    for (int idx = tid; idx < 68 * 28; idx += NT) {
        int r = idx / 28, cc = idx - r * 28;
        int hh = r - 2, ww = cc - 2;
        float v = 0.f;
        if ((unsigned)hh < 64u && (unsigned)ww < 24u) v = Xc[hh * 24 + ww];
        sXp[idx] = v;
    }
    for (int idx = tid; idx < 72 * 28; idx += NT) {
        int r = idx / 28, cc = idx - r * 28;
        int hh = r - 4, ww = cc - 2;
        float v = 0.f;
        if ((unsigned)hh < 64u && (unsigned)ww < 24u) v = Yc[hh * 24 + ww];
        sYT[cc * 73 + r] = v;             // stride 73: coprime with 32 banks
    }
    __syncthreads();

    // ---- Phase B: Y patch statistics (shared across x4 threads) ----
    for (int idx = tid; idx < 24 * 68; idx += NT) {
        int ii = idx / 68, r = idx - ii * 68;
        float s = 0.f, s2 = 0.f;
        #pragma unroll
        for (int dx = 0; dx < 5; ++dx)
            #pragma unroll
            for (int dy = 0; dy < 5; ++dy) {
                float v = sYT[(ii + dx) * 73 + r + dy];
                s += v; s2 = fmaf(v, v, s2);
            }
        float var = fmaxf((s2 - s * s * 0.04f) * (1.f / 24.f), 0.f);
        float2 fv;
        fv.x = s;                          // SF
        fv.y = 1.f / (sqrtf(var) + 0.01f); // 1/Fs
        *(float2*)&sFI[(ii * 68 + r) * 2] = fv;
    }
    __syncthreads();

    // ---- Phase C setup: per-thread fixed (h, 4x) ----
    const int x4 = tid % 6;
    const int h  = tid / 6;               // 0..63
    const int xb = x4 * 4;

    float Xw[5][8];                        // X window rows h..h+4, cols xb..xb+7
    #pragma unroll
    for (int dy = 0; dy < 5; ++dy)
        #pragma unroll
        for (int c = 0; c < 8; ++c)
            Xw[dy][c] = sXp[(h + dy) * 28 + xb + c];

    // in-register X patch stats for the 4 x-positions
    float Em[4], IE[4];
    {
        float colS[8], colQ[8];
        #pragma unroll
        for (int c = 0; c < 8; ++c) {
            float s = 0.f, s2 = 0.f;
            #pragma unroll
            for (int dy = 0; dy < 5; ++dy) {
                float v = Xw[dy][c];
                s += v; s2 = fmaf(v, v, s2);
            }
            colS[c] = s; colQ[c] = s2;
        }
        #pragma unroll
        for (int q = 0; q < 4; ++q) {
            float s  = colS[q] + colS[q+1] + colS[q+2] + colS[q+3] + colS[q+4];
            float s2 = colQ[q] + colQ[q+1] + colQ[q+2] + colQ[q+3] + colQ[q+4];
            float var = fmaxf((s2 - s * s * 0.04f) * (1.f / 24.f), 0.f);
            Em[q] = s * 0.04f;
            IE[q] = 1.f / (25.f * (sqrtf(var) + 0.01f));
        }
    }

    float yw[9][5];                        // Y rows h..h+8, rolling cols
    #pragma unroll
    for (int c = 0; c < 4; ++c) {          // prefill cols 0..3 -> slots 0..3
        const float* yc = &sYT[c * 73 + h];
        #pragma unroll
        for (int dr = 0; dr < 9; ++dr) yw[dr][c] = yc[dr];
    }

    // ---- Phase C: 24 i-steps ----
    #pragma unroll 1
    for (int t5 = 0; t5 < 20; t5 += 5) {
        step_i<0>(t5 + 0, h, tid, sYT, sFI, Xw, yw, Em, IE, outC);
        step_i<1>(t5 + 1, h, tid, sYT, sFI, Xw, yw, Em, IE, outC);
        step_i<2>(t5 + 2, h, tid, sYT, sFI, Xw, yw, Em, IE, outC);
        step_i<3>(t5 + 3, h, tid, sYT, sFI, Xw, yw, Em, IE, outC);
        step_i<4>(t5 + 4, h, tid, sYT, sFI, Xw, yw, Em, IE, outC);
    }
    step_i<0>(20, h, tid, sYT, sFI, Xw, yw, Em, IE, outC);
    step_i<1>(21, h, tid, sYT, sFI, Xw, yw, Em, IE, outC);
    step_i<2>(22, h, tid, sYT, sFI, Xw, yw, Em, IE, outC);
    step_i<3>(23, h, tid, sYT, sFI, Xw, yw, Em, IE, outC);
}

extern "C" void kernel_launch(void* const* d_in, const int* in_sizes, int n_in,
                              void* d_out, int out_size, void* d_ws, size_t ws_size,
                              hipStream_t stream) {
    const float* X = (const float*)d_in[0];
    const float* Y = (const float*)d_in[1];
    float* out = (float*)d_out;
    ncc_kernel<<<dim3(16 * 32), dim3(NT), 0, stream>>>(X, Y, out);
}